// Round 8
// baseline (518.287 us; speedup 1.0000x reference)
//
#include <hip/hip_runtime.h>
#include <hip/hip_bf16.h>

#define NTOK 4096
#define DDIM 1024
#define NEXP 8
#define FDIM 4096
#define MAXTILES 40

typedef __attribute__((ext_vector_type(4))) float f32x4;
typedef __attribute__((ext_vector_type(8))) short bf16x8;

#define GLDS(g, l) __builtin_amdgcn_global_load_lds( \
    (const __attribute__((address_space(1))) unsigned int*)(g), \
    (__attribute__((address_space(3))) unsigned int*)(l), 16, 0, 0)

// ---------------- route: no global atomics. Writes xs (bf16), amax[], partial[256][16] ----
__global__ __launch_bounds__(256) void route_kernel(
    const float* __restrict__ x,         // [NTOK, D]
    const float* __restrict__ w_switch,  // [D, E]
    const float* __restrict__ b_switch,  // [E]
    __hip_bfloat16* __restrict__ xs,     // [NTOK, D]
    int* __restrict__ amax_arr,          // [NTOK]
    float* __restrict__ partial)         // [256][16]: 0..7 prob sums, 8..15 counts
{
    const int tid = threadIdx.x;
    const int wave = tid >> 6, lane = tid & 63;
    __shared__ float pr[4][16];

    float wacc[16];
#pragma unroll
    for (int j = 0; j < 16; j++) wacc[j] = 0.0f;

    for (int i = 0; i < 4; i++) {
        const int n = blockIdx.x * 16 + wave * 4 + i;
        const float4* xr = (const float4*)(x + (size_t)n * DDIM);
        float4 xv[4];
#pragma unroll
        for (int j = 0; j < 4; j++) xv[j] = xr[lane + j * 64];

        float acc[NEXP];
#pragma unroll
        for (int e = 0; e < NEXP; e++) acc[e] = 0.0f;
#pragma unroll
        for (int j = 0; j < 4; j++) {
            const int dbase = (lane + j * 64) * 4;
#pragma unroll
            for (int c = 0; c < 4; c++) {
                const float4* wr = (const float4*)(w_switch + (size_t)(dbase + c) * NEXP);
                float4 w0 = wr[0], w1 = wr[1];
                float xvc = ((const float*)&xv[j])[c];
                acc[0] += xvc * w0.x; acc[1] += xvc * w0.y;
                acc[2] += xvc * w0.z; acc[3] += xvc * w0.w;
                acc[4] += xvc * w1.x; acc[5] += xvc * w1.y;
                acc[6] += xvc * w1.z; acc[7] += xvc * w1.w;
            }
        }
#pragma unroll
        for (int e = 0; e < NEXP; e++) {
            float v = acc[e];
#pragma unroll
            for (int off = 32; off > 0; off >>= 1) v += __shfl_xor(v, off, 64);
            acc[e] = v;
        }
        float mx = -1e30f;
#pragma unroll
        for (int e = 0; e < NEXP; e++) {
            acc[e] += b_switch[e];
            mx = fmaxf(mx, acc[e]);
        }
        float sum = 0.0f;
#pragma unroll
        for (int e = 0; e < NEXP; e++) { acc[e] = __expf(acc[e] - mx); sum += acc[e]; }
        float inv = 1.0f / sum;
        float pmax = -1.0f; int amax = 0;
#pragma unroll
        for (int e = 0; e < NEXP; e++) {
            float p = acc[e] * inv;
            acc[e] = p;
            if (p > pmax) { pmax = p; amax = e; }
        }
#pragma unroll
        for (int e = 0; e < NEXP; e++) {
            wacc[e] += acc[e];
            wacc[8 + e] += (amax == e) ? 1.0f : 0.0f;
        }
        if (lane == 0) amax_arr[n] = amax;
#pragma unroll
        for (int j = 0; j < 4; j++) {
            ushort4 pk;
            __hip_bfloat16* pp = (__hip_bfloat16*)&pk;
            pp[0] = __float2bfloat16(xv[j].x * pmax);
            pp[1] = __float2bfloat16(xv[j].y * pmax);
            pp[2] = __float2bfloat16(xv[j].z * pmax);
            pp[3] = __float2bfloat16(xv[j].w * pmax);
            *(ushort4*)(xs + (size_t)n * DDIM + (lane + j * 64) * 4) = pk;
        }
    }
    if (lane == 0) {
#pragma unroll
        for (int j = 0; j < 16; j++) pr[wave][j] = wacc[j];
    }
    __syncthreads();
    if (tid < 16)
        partial[blockIdx.x * 16 + tid] = pr[0][tid] + pr[1][tid] + pr[2][tid] + pr[3][tid];
}

// ---------------- bucket + finalize merged: one block, ecnt stays in LDS ----------------
__global__ __launch_bounds__(1024) void bucket_finalize_kernel(
    const int* __restrict__ amax_arr, const float* __restrict__ partial,
    int* __restrict__ bucket, int* __restrict__ ecnt,
    float* __restrict__ out_tail, int* __restrict__ table)
{
    __shared__ int ctr[NEXP];
    __shared__ float red[16][16];
    if (threadIdx.x < NEXP) ctr[threadIdx.x] = 0;
    __syncthreads();
    const int lane = threadIdx.x & 63;
    for (int c = 0; c < NTOK; c += 1024) {
        int t = c + threadIdx.x;
        int a = amax_arr[t];
#pragma unroll
        for (int e = 0; e < NEXP; e++) {
            bool my = (a == e);
            unsigned long long mask = __ballot(my);
            int cnt = __popcll(mask);
            int base = 0;
            if (lane == 0 && cnt) base = atomicAdd(&ctr[e], cnt);
            base = __shfl(base, 0, 64);
            if (my) {
                int rank = __popcll(mask & ((1ull << lane) - 1ull));
                bucket[e * NTOK + base + rank] = t;
            }
        }
    }
    // prob-sum reduction (first 256 threads)
    if (threadIdx.x < 256) {
        const int j = threadIdx.x & 15, g = threadIdx.x >> 4;
        float s = 0.0f;
        for (int k = 0; k < 16; k++) s += partial[(size_t)(g + k * 16) * 16 + j];
        red[g][j] = s;
    }
    __syncthreads();
    if (threadIdx.x < NEXP) ecnt[threadIdx.x] = ctr[threadIdx.x];
    if (threadIdx.x < 16) {
        float t2 = 0.0f;
        for (int k = 0; k < 16; k++) t2 += red[k][threadIdx.x];
        int dst = (threadIdx.x < 8) ? (8 + threadIdx.x) : (threadIdx.x - 8);
        out_tail[dst] = t2;
    }
    if (threadIdx.x == 16) out_tail[16] = 0.0f;  // n_dropped
    if (threadIdx.x == 0) {
        int idx = 0;
        for (int e = 0; e < NEXP; e++) {
            int cnt2 = ctr[e];
            for (int m0 = 0; m0 < cnt2; m0 += 128) table[idx++] = (e << 16) | m0;
        }
        for (; idx < MAXTILES; idx++) table[idx] = -1;
    }
}

// ---------------- grouped GEMM body: 128x128, BK=64, B = ORIGINAL fp32 [K][N] layout -----
// NO separate transpose/convert kernel. Per K-step:
//   A (bf16, token-gathered): GLDS with pre-swizzled source column (R6 path, unchanged).
//   B (fp32 w1/w2 direct): each thread loads an 8k x 4n fp32 micro-tile (float4, coalesced
//   along N), converts to bf16, transposes in-register (compile-time indices only), and
//   ds_write_b128 K-contiguous 16B runs into Bsm with the SAME XOR involution the reader
//   uses: physical slot = kg ^ (n&7)  <->  reader slot = chunk ^ (row&7). Read path and
//   MFMA/epilogue are verbatim R6 (proven: 0 read conflicts).
// This deletes 384 MB of transpose round-trip at the cost of fp32-width B fetches.
// MODE 0: h = bf16(relu(acc + bias)), KS=1.
// MODE 1: unsafeAtomicAdd fp32 into zeroed out; z==0 block also adds bias.
template <int MODE, int K, int NN, int KS, int NX>
__device__ __forceinline__ void gemm_body(
    const __hip_bfloat16* __restrict__ A,
    const float* __restrict__ W,     // [E][K][NN] fp32, original layout
    const float* __restrict__ bias,
    const int* __restrict__ bucket,
    const int* __restrict__ ecnt,
    const int* __restrict__ table,
    void* __restrict__ Out)
{
    const int bid = blockIdx.x;
    const int xcd = bid & 7;
    const int q = bid >> 3;
    const int x = q % NX;
    const int yk = (q / NX) % (MAXTILES / 8);
    const int z = q / (NX * (MAXTILES / 8));
    const int y = xcd + 8 * yk;

    const int entry = table[y];
    if (entry < 0) return;
    const int e = entry >> 16;
    const int m0 = entry & 0xffff;
    const int cnt = ecnt[e];
    const int n0 = x * 128;
    const int kbase = (K / KS) * z;

    __shared__ __align__(16) __hip_bfloat16 Asm[128 * 64];  // 16 KB [128 tok][64 k]
    __shared__ __align__(16) __hip_bfloat16 Bsm[128 * 64];  // 16 KB [128 n][64 k], swizzled
    __shared__ int toks[128];

    const int tid = threadIdx.x;
    if (tid < 128) {
        int r = m0 + tid;
        toks[tid] = bucket[e * NTOK + (r < cnt ? r : cnt - 1)];
    }
    __syncthreads();

    const int wave = tid >> 6, lane = tid & 63;

    // ---- A staging (GLDS, R6 unchanged): wave w covers token-rows w*32..w*32+31
    const int srow = lane >> 3;                   // row within 8-row staging group
    const int swzcol = ((lane & 7) ^ srow) * 16;  // pre-swizzled SOURCE byte column
    const char* pA[4];
#pragma unroll
    for (int i = 0; i < 4; i++)
        pA[i] = (const char*)(A + (size_t)toks[wave * 32 + i * 8 + srow] * K + kbase) + swzcol;

    // ---- B staging (reg-transpose from fp32 [K][NN]): thread owns 8k x 4n micro-tile
    const int ng = tid & 31;   // n-group of 4 (cols n0 + ng*4 .. +4)
    const int kg = tid >> 5;   // 0..7: k-group of 8
    const float* pW = W + ((size_t)e * K + kbase + kg * 8) * NN + n0 + ng * 4;
    // LDS write targets: 4 rows n = ng*4+c, 16B at slot (kg ^ (n&7))
    unsigned bofs[4];
#pragma unroll
    for (int c = 0; c < 4; c++) {
        const int n = ng * 4 + c;
        bofs[c] = n * 128 + ((kg ^ (n & 7)) * 16);
    }

    const int wm = wave & 1, wn = wave >> 1;
    const int r16 = lane & 15, kq16 = lane >> 4;
    const int r7x = (r16 & 7) * 16;               // XOR term for swizzled ds_read

    f32x4 acc[4][4];
#pragma unroll
    for (int t = 0; t < 4; t++)
#pragma unroll
        for (int u = 0; u < 4; u++) acc[t][u] = (f32x4){0.f, 0.f, 0.f, 0.f};

    for (int k0 = 0; k0 < K / KS; k0 += 64) {
        // A: 4 GLDS per wave (8 rows x 128B each, linear dest)
#pragma unroll
        for (int i = 0; i < 4; i++) {
            GLDS(pA[i], (char*)Asm + (wave * 32 + i * 8) * 128 + lane * 16);
            pA[i] += 128;
        }
        // B: 8 coalesced float4 loads (512B runs per half-wave along N)
        float4 v[8];
#pragma unroll
        for (int j = 0; j < 8; j++) v[j] = *(const float4*)(pW + (size_t)j * NN);
        pW += (size_t)64 * NN;
        // convert + in-register transpose + 4x ds_write_b128 (K-contiguous runs)
#pragma unroll
        for (int c = 0; c < 4; c++) {
            __hip_bfloat16 row[8];
#pragma unroll
            for (int j = 0; j < 8; j++)
                row[j] = __float2bfloat16(((const float*)&v[j])[c]);
            *(uint4*)((char*)Bsm + bofs[c]) = *(const uint4*)row;
        }
        __syncthreads();

#pragma unroll
        for (int ksub = 0; ksub < 2; ksub++) {
            const int slot = ((kq16 + ksub * 4) * 16) ^ r7x;  // swizzled column byte offset
            bf16x8 a[4], b[4];
#pragma unroll
            for (int t = 0; t < 4; t++)
                a[t] = *(const bf16x8*)((const char*)Asm +
                        (wm * 64 + t * 16 + r16) * 128 + slot);
#pragma unroll
            for (int u = 0; u < 4; u++)
                b[u] = *(const bf16x8*)((const char*)Bsm +
                        (wn * 64 + u * 16 + r16) * 128 + slot);
#pragma unroll
            for (int t = 0; t < 4; t++)
#pragma unroll
                for (int u = 0; u < 4; u++)
                    acc[t][u] = __builtin_amdgcn_mfma_f32_16x16x32_bf16(a[t], b[u], acc[t][u], 0, 0, 0);
        }
        __syncthreads();
    }

    const int quad = lane >> 4, l15 = lane & 15;
    float bv[4];
#pragma unroll
    for (int u = 0; u < 4; u++) {
        if (MODE == 0)
            bv[u] = bias[(size_t)e * NN + n0 + wn * 64 + u * 16 + l15];
        else
            bv[u] = (z == 0) ? bias[(size_t)e * NN + n0 + wn * 64 + u * 16 + l15] : 0.0f;
    }
#pragma unroll
    for (int t = 0; t < 4; t++) {
#pragma unroll
        for (int rr = 0; rr < 4; rr++) {
            int row = wm * 64 + t * 16 + quad * 4 + rr;
            if (m0 + row < cnt) {
                int tok = toks[row];
#pragma unroll
                for (int u = 0; u < 4; u++) {
                    int col = n0 + wn * 64 + u * 16 + l15;
                    float vv = acc[t][u][rr] + bv[u];
                    if (MODE == 0) {
                        vv = fmaxf(vv, 0.0f);
                        ((__hip_bfloat16*)Out)[(size_t)tok * NN + col] = __float2bfloat16(vv);
                    } else {
                        unsafeAtomicAdd(&((float*)Out)[(size_t)tok * NN + col], vv);
                    }
                }
            }
        }
    }
}

__global__ __launch_bounds__(256, 4) void gemm_ffn1(
    const __hip_bfloat16* __restrict__ A, const float* __restrict__ W,
    const float* __restrict__ bias, const int* __restrict__ bucket,
    const int* __restrict__ ecnt, const int* __restrict__ table, void* __restrict__ Out)
{
    gemm_body<0, DDIM, FDIM, 1, FDIM / 128>(A, W, bias, bucket, ecnt, table, Out);
}

__global__ __launch_bounds__(256, 4) void gemm_ffn2(
    const __hip_bfloat16* __restrict__ A, const float* __restrict__ W,
    const float* __restrict__ bias, const int* __restrict__ bucket,
    const int* __restrict__ ecnt, const int* __restrict__ table, void* __restrict__ Out)
{
    gemm_body<1, FDIM, DDIM, 4, DDIM / 128>(A, W, bias, bucket, ecnt, table, Out);
}

extern "C" void kernel_launch(void* const* d_in, const int* in_sizes, int n_in,
                              void* d_out, int out_size, void* d_ws, size_t ws_size,
                              hipStream_t stream) {
    const float* x        = (const float*)d_in[0];
    const float* w_switch = (const float*)d_in[1];
    const float* b_switch = (const float*)d_in[2];
    const float* w1       = (const float*)d_in[3];
    const float* b1       = (const float*)d_in[4];
    const float* w2       = (const float*)d_in[5];
    const float* b2       = (const float*)d_in[6];

    float* out = (float*)d_out;
    float* out_tail = out + (size_t)NTOK * DDIM;

    char* ws = (char*)d_ws;
    __hip_bfloat16* xs = (__hip_bfloat16*)(ws);                        // 8 MB
    __hip_bfloat16* h  = (__hip_bfloat16*)(ws + 8388608ull);           // 32 MB
    int* bucket        = (int*)(ws + 109051904ull);                    // 128 KB
    int* amax_arr      = (int*)(ws + 109182976ull);                    // 16 KB
    float* partial     = (float*)(ws + 109199360ull);                  // 16 KB
    int* ecnt          = (int*)(ws + 109215744ull);                    // 32 B
    int* table         = (int*)(ws + 109215776ull);                    // 160 B

    // zero the accumulation target (b2 bias folded into z==0 GEMM blocks)
    hipMemsetAsync(out, 0, (size_t)NTOK * DDIM * sizeof(float), stream);

    hipLaunchKernelGGL(route_kernel, dim3(256), dim3(256), 0, stream,
                       x, w_switch, b_switch, xs, amax_arr, partial);
    hipLaunchKernelGGL(bucket_finalize_kernel, dim3(1), dim3(1024), 0, stream,
                       amax_arr, partial, bucket, ecnt, out_tail, table);

    // ffn1: xs @ w1 (fp32 B consumed directly, transposed in-kernel)
    hipLaunchKernelGGL(gemm_ffn1, dim3((FDIM / 128) * MAXTILES), dim3(256), 0, stream,
                       xs, w1, b1, bucket, ecnt, table, (void*)h);

    // ffn2: h @ w2 (fp32 B consumed directly), atomic accumulate into out
    hipLaunchKernelGGL(gemm_ffn2, dim3((DDIM / 128) * MAXTILES * 4), dim3(256), 0, stream,
                       h, w2, b2, bucket, ecnt, table, (void*)out);
}